// Round 4
// baseline (2275.876 us; speedup 1.0000x reference)
//
#include <hip/hip_runtime.h>
#include <stdint.h>

#define NLAYER 5
#define EMB    300
#define EMBP   320
#define HID    600
#define HIDP   640
#define BNEPS  1e-5f

typedef __attribute__((ext_vector_type(8))) __bf16 bfrag;
typedef __attribute__((ext_vector_type(8))) short s16x8;
typedef __attribute__((ext_vector_type(4))) float f32x4;
typedef __attribute__((ext_vector_type(4))) unsigned short u16x4;

__device__ __forceinline__ float b2f(unsigned short u){
  union { unsigned int i; float f; } v; v.i = ((unsigned int)u) << 16; return v.f;
}
__device__ __forceinline__ unsigned short f2b(float f){
  unsigned int u = __float_as_uint(f);
  u += 0x7FFFu + ((u >> 16) & 1u);
  return (unsigned short)(u >> 16);
}
__device__ __forceinline__ void gload16(const void* g, void* l){
  __builtin_amdgcn_global_load_lds(
      (const __attribute__((address_space(1))) void*)g,
      (__attribute__((address_space(3))) void*)l,
      16, 0, 0);
}

// ---------------- setup kernels ----------------

__global__ void k_canary(float* __restrict__ p, int n){
  for (int i = blockIdx.x*blockDim.x + threadIdx.x; i < n; i += gridDim.x*blockDim.x)
    p[i] = 1.0f;   // diagnostic: "never overwritten" != "zeros"
}

__global__ void k_zero(unsigned int* __restrict__ p, int n){
  int i = blockIdx.x*blockDim.x + threadIdx.x;
  if (i < n) p[i] = 0u;
}

__global__ void k_hist(const int* __restrict__ ei, int E, int N, int* __restrict__ deg){
  int e = blockIdx.x*blockDim.x + threadIdx.x;
  if (e >= E + N) return;
  int dst = (e < E) ? ei[E + e] : (e - E);
  atomicAdd(&deg[dst], 1);
}

__global__ void k_scan(const int* __restrict__ deg, int* __restrict__ rowptr,
                       int* __restrict__ cursor, int N)
{
  __shared__ int sd[1024];
  __shared__ int carry;
  const int tid = threadIdx.x;
  if (tid == 0) { carry = 0; rowptr[0] = 0; }
  __syncthreads();
  for (int base = 0; base < N; base += 1024) {
    const int i = base + tid;
    const int v = (i < N) ? deg[i] : 0;
    sd[tid] = v;
    __syncthreads();
    for (int offp = 1; offp < 1024; offp <<= 1) {
      int t = (tid >= offp) ? sd[tid - offp] : 0;
      __syncthreads();
      sd[tid] += t;
      __syncthreads();
    }
    const int incl = sd[tid] + carry;
    if (i < N) { rowptr[i+1] = incl; cursor[i] = incl - v; }
    __syncthreads();
    if (tid == 1023) carry = incl;
    __syncthreads();
  }
}

__global__ void k_fill(const int* __restrict__ ei, const int* __restrict__ ea,
                       int E, int N, int* __restrict__ cursor,
                       unsigned int* __restrict__ entries)
{
  int e = blockIdx.x*blockDim.x + threadIdx.x;
  if (e >= E + N) return;
  int src, dst, bt, bd;
  if (e < E) { src = ei[e]; dst = ei[E + e]; bt = ea[2*e]; bd = ea[2*e + 1]; }
  else       { src = e - E; dst = src;       bt = 4;       bd = 0; }
  int pos = atomicAdd(&cursor[dst], 1);
  entries[pos] = (unsigned)src | ((unsigned)bt << 20) | ((unsigned)bd << 24);
}

// W: [NLAYER][K][Ncol] f32 -> WT: [NLAYER][Np][Kp] bf16 (transposed, zero-padded)
__global__ void k_prep_w(const float* __restrict__ W, unsigned short* __restrict__ WT,
                         int K, int Ncol, int Kp, int Np)
{
  int i = blockIdx.x*blockDim.x + threadIdx.x;
  int total = NLAYER * Np * Kp;
  if (i >= total) return;
  int l = i / (Np * Kp);
  int rem = i - l * (Np * Kp);
  int n = rem / Kp;
  int k = rem - n * Kp;
  unsigned short v = 0;
  if (n < Ncol && k < K) v = f2b(W[(size_t)l*K*Ncol + (size_t)k*Ncol + n]);
  WT[i] = v;
}

// src: [R][SC] f32 -> dst: [R][DC] bf16 zero-padded
__global__ void k_pad(const float* __restrict__ src, unsigned short* __restrict__ dst,
                      int R, int SC, int DC)
{
  int i = blockIdx.x*blockDim.x + threadIdx.x;
  if (i >= R * DC) return;
  int r = i / DC, c = i - r * DC;
  dst[i] = (c < SC) ? f2b(src[r*SC + c]) : (unsigned short)0;
}

// bias: [R][SC] f32 -> [R][DC] f32 zero-padded
__global__ void k_padb(const float* __restrict__ src, float* __restrict__ dst,
                       int R, int SC, int DC)
{
  int i = blockIdx.x*blockDim.x + threadIdx.x;
  if (i >= R * DC) return;
  int r = i / DC, c = i - r * DC;
  dst[i] = (c < SC) ? src[r*SC + c] : 0.f;
}

// h0[n] = x_emb1[x[n,0]] + x_emb2[x[n,1]]  (padded bf16 tables -> pad cols are 0)
__global__ void k_h0(const int* __restrict__ x, const unsigned short* __restrict__ x1p,
                     const unsigned short* __restrict__ x2p, unsigned short* __restrict__ h, int N)
{
  const int w = threadIdx.x >> 6, lane = threadIdx.x & 63;
  const int n = blockIdx.x * 4 + w;
  if (n >= N || lane >= 40) return;
  const int c0 = lane * 8;
  const int a = x[2*n], b = x[2*n + 1];
  s16x8 va = *(const s16x8*)&x1p[(size_t)a*EMBP + c0];
  s16x8 vb = *(const s16x8*)&x2p[(size_t)b*EMBP + c0];
  s16x8 o;
#pragma unroll
  for (int j = 0; j < 8; j++)
    o[j] = (short)f2b(b2f((unsigned short)va[j]) + b2f((unsigned short)vb[j]));
  *(s16x8*)&h[(size_t)n*EMBP + c0] = o;
}

// ---------------- fused gather + GEMM1 ----------------
// Per block: build 64-row aggr tile in LDS from graph, then
// hid[64 x 640] = relu(aggr[64 x 320] * W1T[640 x 320]^T + b1), written to global.
__global__ __launch_bounds__(256) void k_gather_gemm1(
    const unsigned short* __restrict__ h,       // [N][EMBP]
    const int* __restrict__ rowptr,
    const unsigned int* __restrict__ entries,
    const unsigned short* __restrict__ t1,      // [6][EMBP] layer tables (bf16)
    const unsigned short* __restrict__ t2,      // [3][EMBP]
    const unsigned short* __restrict__ W1T,     // [HIDP][EMBP] bf16
    const float* __restrict__ b1,               // [HIDP]
    unsigned short* __restrict__ hid,           // [chunkRows][HIDP] (chunk-local)
    int nBase, int N)
{
  __shared__ __align__(16) unsigned short aggr[64][328];  // +8 pad: bank spread
  const int tid = threadIdx.x, w = tid >> 6, lane = tid & 63;

  // ---- phase A: gather 64 rows (wave w -> local rows w*16..w*16+15) ----
  {
    const int c0 = lane * 8;   // valid for lane < 40
    for (int i = 0; i < 16; ++i) {
      const int lr = w*16 + i;
      const int n  = nBase + blockIdx.x*64 + lr;
      if (lane < 40) {
        float s[8] = {0.f,0.f,0.f,0.f,0.f,0.f,0.f,0.f};
        if (n < N) {
          const int beg = rowptr[n], end = rowptr[n+1];
          int c6[6] = {0,0,0,0,0,0};
          int c3[3] = {0,0,0};
          for (int e = beg; e < end; ++e) {
            const unsigned int p = entries[e];
            const int src = p & 0xFFFFF;
            const int bt = (p >> 20) & 7, bd = (p >> 24) & 3;
#pragma unroll
            for (int t = 0; t < 6; t++) c6[t] += (bt == t);
#pragma unroll
            for (int t = 0; t < 3; t++) c3[t] += (bd == t);
            s16x8 hv = *(const s16x8*)&h[(size_t)src*EMBP + c0];
#pragma unroll
            for (int j = 0; j < 8; j++) s[j] += b2f((unsigned short)hv[j]);
          }
#pragma unroll
          for (int t = 0; t < 6; t++) if (c6[t]) {
            s16x8 tv = *(const s16x8*)&t1[t*EMBP + c0];
            const float f = (float)c6[t];
#pragma unroll
            for (int j = 0; j < 8; j++) s[j] += f * b2f((unsigned short)tv[j]);
          }
#pragma unroll
          for (int t = 0; t < 3; t++) if (c3[t]) {
            s16x8 tv = *(const s16x8*)&t2[t*EMBP + c0];
            const float f = (float)c3[t];
#pragma unroll
            for (int j = 0; j < 8; j++) s[j] += f * b2f((unsigned short)tv[j]);
          }
        }
        s16x8 ov;
#pragma unroll
        for (int j = 0; j < 8; j++) ov[j] = (short)f2b(s[j]);
        *(s16x8*)&aggr[lr][c0] = ov;
      }
    }
  }
  __syncthreads();

  // ---- phase B: GEMM1 over 5 n-chunks of 128 cols; wave w owns cols w*32 ----
  const int cl = lane & 15, kg = lane >> 4;
  for (int nc = 0; nc < 5; ++nc) {
    const int nb = nc*128 + w*32;
    f32x4 acc[4][2];
#pragma unroll
    for (int mf = 0; mf < 4; mf++)
#pragma unroll
      for (int nf = 0; nf < 2; nf++)
        acc[mf][nf] = (f32x4){0.f,0.f,0.f,0.f};
    for (int kk = 0; kk < EMBP; kk += 32) {
      bfrag af[4], bfv[2];
#pragma unroll
      for (int mf = 0; mf < 4; mf++)
        af[mf] = *(const bfrag*)&aggr[mf*16 + cl][kg*8 + kk];
#pragma unroll
      for (int nf = 0; nf < 2; nf++)
        bfv[nf] = *(const bfrag*)&W1T[(size_t)(nb + nf*16 + cl)*EMBP + kg*8 + kk];
#pragma unroll
      for (int mf = 0; mf < 4; mf++)
#pragma unroll
        for (int nf = 0; nf < 2; nf++)
          acc[mf][nf] = __builtin_amdgcn_mfma_f32_16x16x32_bf16(af[mf], bfv[nf], acc[mf][nf], 0, 0, 0);
    }
#pragma unroll
    for (int mf = 0; mf < 4; mf++) {
#pragma unroll
      for (int nf = 0; nf < 2; nf++) {
        const int col = nb + nf*16 + cl;
        const float bv = b1[col];
        const int row0 = blockIdx.x*64 + mf*16 + kg*4;
        f32x4 v = acc[mf][nf];
#pragma unroll
        for (int r = 0; r < 4; r++)
          hid[(size_t)(row0 + r)*HIDP + col] = f2b(fmaxf(v[r] + bv, 0.f));
      }
    }
  }
}

// ---------------- GEMM2: d_out[chunk x 300] (f32) = hid * W2T^T + b2 ----
__global__ __launch_bounds__(256) void k_gemm2(
    const unsigned short* __restrict__ A,      // hid chunk [rows][HIDP]
    const unsigned short* __restrict__ Bt,     // W2T [EMBP][HIDP] bf16
    const float* __restrict__ bias,            // [EMBP]
    float* __restrict__ out,                   // d_out [N][EMB] f32
    int nBase, int N)
{
  __shared__ __align__(16) unsigned short As[128*32];
  __shared__ __align__(16) unsigned short Bs[64*32];
  const int tid  = threadIdx.x;
  const int w    = tid >> 6;
  const int lane = tid & 63;
  const int wr = w >> 1, wc = w & 1;
  const int m0 = blockIdx.x * 128;
  const int n0 = blockIdx.y * 64;

  const int lrow = lane >> 2;
  const int lk   = (lane & 3) * 8;

  const unsigned short* Ag = A  + (size_t)(m0 + w*16 + lrow) * HIDP + lk;
  const unsigned short* Bg = Bt + (size_t)(n0 + w*16 + lrow) * HIDP + lk;

  f32x4 acc[4][2];
#pragma unroll
  for (int i = 0; i < 4; i++)
#pragma unroll
    for (int j = 0; j < 2; j++)
      acc[i][j] = (f32x4){0.f, 0.f, 0.f, 0.f};

  for (int k0 = 0; k0 < HIDP; k0 += 32) {
    gload16(Ag + k0,                   &As[(w*16)*32]);
    gload16(Ag + (size_t)64*HIDP + k0, &As[(w*16 + 64)*32]);
    gload16(Bg + k0,                   &Bs[(w*16)*32]);
    __syncthreads();
    bfrag af[4], bfv[2];
#pragma unroll
    for (int mf = 0; mf < 4; mf++)
      af[mf] = *(const bfrag*)&As[(wr*64 + mf*16 + (lane & 15))*32 + (lane >> 4)*8];
#pragma unroll
    for (int nf = 0; nf < 2; nf++)
      bfv[nf] = *(const bfrag*)&Bs[(wc*32 + nf*16 + (lane & 15))*32 + (lane >> 4)*8];
#pragma unroll
    for (int mf = 0; mf < 4; mf++)
#pragma unroll
      for (int nf = 0; nf < 2; nf++)
        acc[mf][nf] = __builtin_amdgcn_mfma_f32_16x16x32_bf16(af[mf], bfv[nf], acc[mf][nf], 0, 0, 0);
    __syncthreads();
  }

  const int cl = lane & 15, rg = lane >> 4;
#pragma unroll
  for (int mf = 0; mf < 4; mf++) {
#pragma unroll
    for (int nf = 0; nf < 2; nf++) {
      const int col = n0 + wc*32 + nf*16 + cl;
      if (col >= EMB) continue;
      const float bv = bias[col];
      const int row0 = m0 + wr*64 + mf*16 + rg*4;
      f32x4 v = acc[mf][nf];
#pragma unroll
      for (int r = 0; r < 4; r++) {
        const int grow = nBase + row0 + r;
        if (grow < N)
          out[(size_t)grow*EMB + col] = v[r] + bv;
      }
    }
  }
}

// ---------------- BatchNorm (deterministic, f32 activations) ----------------

__global__ void k_bnstat(const float* __restrict__ out, float* __restrict__ part, int N)
{
  const int c = threadIdx.x;   // 0..319
  float s = 0.f, s2 = 0.f;
  if (c < EMB) {
    for (int r = blockIdx.x; r < N; r += gridDim.x) {
      float v = out[(size_t)r*EMB + c];
      s += v; s2 += v*v;
    }
  }
  part[blockIdx.x*(2*EMBP) + c]        = s;
  part[blockIdx.x*(2*EMBP) + EMBP + c] = s2;
}

__global__ void k_bnfin(const float* __restrict__ part,
                        const float* __restrict__ gamma,
                        const float* __restrict__ beta,
                        float* __restrict__ scl, float* __restrict__ sft, int N, int NB)
{
  const int c = threadIdx.x;
  if (c >= EMBP) return;
  float s = 0.f, s2 = 0.f;
  for (int b = 0; b < NB; b++) {
    s  += part[b*(2*EMBP) + c];
    s2 += part[b*(2*EMBP) + EMBP + c];
  }
  if (c < EMB) {
    float mean = s / (float)N;
    float var  = fmaxf(s2 / (float)N - mean*mean, 0.f);
    float sc = gamma[c] * rsqrtf(var + BNEPS);
    scl[c] = sc;
    sft[c] = beta[c] - mean*sc;
  } else { scl[c] = 0.f; sft[c] = 0.f; }
}

// mid layers: h[n][0..319] = bf16(relu(out*scl+sft)) (pad cols 0). last: f32 in-place.
template<bool LAST>
__global__ void k_bnapply(const float* __restrict__ outv,
                          const float* __restrict__ scl, const float* __restrict__ sft,
                          unsigned short* __restrict__ hdst, float* __restrict__ odst, int N)
{
  int i = blockIdx.x*blockDim.x + threadIdx.x;
  if (i >= N * (EMBP/4)) return;
  const int n = i / (EMBP/4);
  const int c = (i - n*(EMBP/4)) * 4;
  if (LAST) {
    if (c >= EMB) return;
    f32x4 v = *(const f32x4*)&outv[(size_t)n*EMB + c];
    f32x4 o;
#pragma unroll
    for (int j = 0; j < 4; j++) o[j] = v[j]*scl[c+j] + sft[c+j];
    *(f32x4*)&odst[(size_t)n*EMB + c] = o;
  } else {
    u16x4 o;
    if (c < EMB) {
      f32x4 v = *(const f32x4*)&outv[(size_t)n*EMB + c];
#pragma unroll
      for (int j = 0; j < 4; j++) o[j] = f2b(fmaxf(v[j]*scl[c+j] + sft[c+j], 0.f));
    } else {
#pragma unroll
      for (int j = 0; j < 4; j++) o[j] = 0;
    }
    *(u16x4*)&hdst[(size_t)n*EMBP + c] = o;
  }
}

// ---------------- host ----------------

extern "C" void kernel_launch(void* const* d_in, const int* in_sizes, int n_in,
                              void* d_out, int out_size, void* d_ws, size_t ws_size,
                              hipStream_t stream)
{
  (void)n_in;
  const int* x  = (const int*)d_in[0];
  const int* ei = (const int*)d_in[1];
  const int* ea = (const int*)d_in[2];
  const float* xe1 = (const float*)d_in[3];   // f32 params (npz-size evidence)
  const float* xe2 = (const float*)d_in[4];
  const float* ee1 = (const float*)d_in[5];
  const float* ee2 = (const float*)d_in[6];
  const float* W1  = (const float*)d_in[7];
  const float* b1  = (const float*)d_in[8];
  const float* W2  = (const float*)d_in[9];
  const float* b2  = (const float*)d_in[10];
  const float* gam = (const float*)d_in[11];
  const float* bet = (const float*)d_in[12];

  const int N  = in_sizes[0] / 2;
  const int E  = in_sizes[1] / 2;
  const int EN = E + N;
  const int Mp = ((N + 127) / 128) * 128;
  const int R1 = in_sizes[3] / EMB;

  float* dout = (float*)d_out;

  // diagnostic canary: 1.0f everywhere (fully overwritten on success)
  k_canary<<<1024, 256, 0, stream>>>(dout, out_size);

  char* ws = (char*)d_ws;
  size_t off = 0;
  auto alloc = [&](size_t bytes){ size_t o = off; off = (off + bytes + 255) & ~(size_t)255; return o; };

  unsigned short* h      = (unsigned short*)(ws + alloc((size_t)N*EMBP*2));
  unsigned int*  entries = (unsigned int*)(ws + alloc((size_t)EN*4));
  int* rowptr            = (int*)(ws + alloc((size_t)(N+1)*4));
  int* cursor            = (int*)(ws + alloc((size_t)N*4));
  int* deg               = (int*)(ws + alloc((size_t)N*4));
  unsigned short* W1T    = (unsigned short*)(ws + alloc((size_t)NLAYER*HIDP*EMBP*2));
  unsigned short* W2T    = (unsigned short*)(ws + alloc((size_t)NLAYER*EMBP*HIDP*2));
  unsigned short* x1p    = (unsigned short*)(ws + alloc((size_t)R1*EMBP*2));
  unsigned short* x2p    = (unsigned short*)(ws + alloc((size_t)3*EMBP*2));
  unsigned short* e1p    = (unsigned short*)(ws + alloc((size_t)NLAYER*6*EMBP*2));
  unsigned short* e2p    = (unsigned short*)(ws + alloc((size_t)NLAYER*3*EMBP*2));
  float* b1p             = (float*)(ws + alloc((size_t)NLAYER*HIDP*4));
  float* b2p             = (float*)(ws + alloc((size_t)NLAYER*EMBP*4));
  float* part            = (float*)(ws + alloc((size_t)256*2*EMBP*4));
  float* scl             = (float*)(ws + alloc((size_t)EMBP*4));
  float* sft             = (float*)(ws + alloc((size_t)EMBP*4));

  // adaptive hid chunk: as many rows as fit (multiple of 128), up to Mp
  if (off >= ws_size) return;   // canary remains -> diagnostic signature (1.0s)
  size_t avail = ws_size - off;
  size_t maxrows = avail / ((size_t)HIDP*2);
  if (maxrows < 128) return;    // canary remains
  int CH = (maxrows >= (size_t)Mp) ? Mp : (int)(maxrows & ~(size_t)127);
  unsigned short* hidc = (unsigned short*)(ws + off);

  // CSR build
  k_zero<<<(N+255)/256, 256, 0, stream>>>((unsigned int*)deg, N);
  k_hist<<<(EN+255)/256, 256, 0, stream>>>(ei, E, N, deg);
  k_scan<<<1, 1024, 0, stream>>>(deg, rowptr, cursor, N);
  k_fill<<<(EN+255)/256, 256, 0, stream>>>(ei, ea, E, N, cursor, entries);

  // weight/table prep (f32 -> padded bf16 / f32)
  {
    int tot = NLAYER*HIDP*EMBP;
    k_prep_w<<<(tot+255)/256, 256, 0, stream>>>(W1, W1T, EMB, HID, EMBP, HIDP);
    k_prep_w<<<(tot+255)/256, 256, 0, stream>>>(W2, W2T, HID, EMB, HIDP, EMBP);
  }
  k_pad <<<((R1*EMBP)+255)/256, 256, 0, stream>>>(xe1, x1p, R1, EMB, EMBP);
  k_pad <<<((3*EMBP)+255)/256, 256, 0, stream>>>(xe2, x2p, 3, EMB, EMBP);
  k_pad <<<((NLAYER*6*EMBP)+255)/256, 256, 0, stream>>>(ee1, e1p, NLAYER*6, EMB, EMBP);
  k_pad <<<((NLAYER*3*EMBP)+255)/256, 256, 0, stream>>>(ee2, e2p, NLAYER*3, EMB, EMBP);
  k_padb<<<((NLAYER*HIDP)+255)/256, 256, 0, stream>>>(b1, b1p, NLAYER, HID, HIDP);
  k_padb<<<((NLAYER*EMBP)+255)/256, 256, 0, stream>>>(b2, b2p, NLAYER, EMB, EMBP);

  // h0
  k_h0<<<(N+3)/4, 256, 0, stream>>>(x, x1p, x2p, h, N);

  for (int l = 0; l < NLAYER; ++l) {
    for (int base = 0; base < Mp; base += CH) {
      const int rows = (Mp - base < CH) ? (Mp - base) : CH;   // multiple of 128
      k_gather_gemm1<<<rows/64, 256, 0, stream>>>(
          h, rowptr, entries,
          e1p + (size_t)l*6*EMBP, e2p + (size_t)l*3*EMBP,
          W1T + (size_t)l*HIDP*EMBP, b1p + (size_t)l*HIDP,
          hidc, base, N);
      dim3 g2(rows/128, EMBP/64);
      k_gemm2<<<g2, 256, 0, stream>>>(
          hidc, W2T + (size_t)l*EMBP*HIDP, b2p + (size_t)l*EMBP,
          dout, base, N);
    }
    k_bnstat<<<256, EMBP, 0, stream>>>(dout, part, N);
    k_bnfin<<<1, EMBP, 0, stream>>>(part, gam + (size_t)l*EMB, bet + (size_t)l*EMB, scl, sft, N, 256);
    int tot = N * (EMBP/4);
    if (l < NLAYER - 1)
      k_bnapply<false><<<(tot+255)/256, 256, 0, stream>>>(dout, scl, sft, h, nullptr, N);
    else
      k_bnapply<true><<<(tot+255)/256, 256, 0, stream>>>(dout, scl, sft, nullptr, dout, N);
  }
}

// Round 5
// 1568.269 us; speedup vs baseline: 1.4512x; 1.4512x over previous
//
#include <hip/hip_runtime.h>
#include <stdint.h>

#define NLAYER 5
#define EMB    300
#define EMBP   320
#define EMBP2  384
#define HID    600
#define HIDP   640
#define BNEPS  1e-5f

typedef __attribute__((ext_vector_type(8))) __bf16 bfrag;
typedef __attribute__((ext_vector_type(8))) short s16x8;
typedef __attribute__((ext_vector_type(4))) float f32x4;
typedef __attribute__((ext_vector_type(4))) unsigned short u16x4;

__device__ __forceinline__ float b2f(unsigned short u){
  union { unsigned int i; float f; } v; v.i = ((unsigned int)u) << 16; return v.f;
}
__device__ __forceinline__ unsigned short f2b(float f){
  unsigned int u = __float_as_uint(f);
  u += 0x7FFFu + ((u >> 16) & 1u);
  return (unsigned short)(u >> 16);
}
__device__ __forceinline__ void gload16(const void* g, void* l){
  __builtin_amdgcn_global_load_lds(
      (const __attribute__((address_space(1))) void*)g,
      (__attribute__((address_space(3))) void*)l,
      16, 0, 0);
}

// ---------------- setup kernels ----------------

__global__ void k_canary(float* __restrict__ p, int n){
  for (int i = blockIdx.x*blockDim.x + threadIdx.x; i < n; i += gridDim.x*blockDim.x)
    p[i] = 1.0f;
}

__global__ void k_zero(unsigned int* __restrict__ p, int n){
  int i = blockIdx.x*blockDim.x + threadIdx.x;
  if (i < n) p[i] = 0u;
}

__global__ void k_hist(const int* __restrict__ ei, int E, int N, int* __restrict__ deg){
  int e = blockIdx.x*blockDim.x + threadIdx.x;
  if (e >= E + N) return;
  int dst = (e < E) ? ei[E + e] : (e - E);
  atomicAdd(&deg[dst], 1);
}

__global__ void k_scan(const int* __restrict__ deg, int* __restrict__ rowptr,
                       int* __restrict__ cursor, int N)
{
  __shared__ int sd[1024];
  __shared__ int carry;
  const int tid = threadIdx.x;
  if (tid == 0) { carry = 0; rowptr[0] = 0; }
  __syncthreads();
  for (int base = 0; base < N; base += 1024) {
    const int i = base + tid;
    const int v = (i < N) ? deg[i] : 0;
    sd[tid] = v;
    __syncthreads();
    for (int offp = 1; offp < 1024; offp <<= 1) {
      int t = (tid >= offp) ? sd[tid - offp] : 0;
      __syncthreads();
      sd[tid] += t;
      __syncthreads();
    }
    const int incl = sd[tid] + carry;
    if (i < N) { rowptr[i+1] = incl; cursor[i] = incl - v; }
    __syncthreads();
    if (tid == 1023) carry = incl;
    __syncthreads();
  }
}

__global__ void k_fill(const int* __restrict__ ei, const int* __restrict__ ea,
                       int E, int N, int* __restrict__ cursor,
                       unsigned int* __restrict__ entries)
{
  int e = blockIdx.x*blockDim.x + threadIdx.x;
  if (e >= E + N) return;
  int src, dst, bt, bd;
  if (e < E) { src = ei[e]; dst = ei[E + e]; bt = ea[2*e]; bd = ea[2*e + 1]; }
  else       { src = e - E; dst = src;       bt = 4;       bd = 0; }
  int pos = atomicAdd(&cursor[dst], 1);
  entries[pos] = (unsigned)src | ((unsigned)bt << 20) | ((unsigned)bd << 24);
}

// W: [NLAYER][K][Ncol] f32 -> WT: [NLAYER][Np][Kp] bf16 (transposed, zero-padded)
__global__ void k_prep_w(const float* __restrict__ W, unsigned short* __restrict__ WT,
                         int K, int Ncol, int Kp, int Np)
{
  int i = blockIdx.x*blockDim.x + threadIdx.x;
  int total = NLAYER * Np * Kp;
  if (i >= total) return;
  int l = i / (Np * Kp);
  int rem = i - l * (Np * Kp);
  int n = rem / Kp;
  int k = rem - n * Kp;
  unsigned short v = 0;
  if (n < Ncol && k < K) v = f2b(W[(size_t)l*K*Ncol + (size_t)k*Ncol + n]);
  WT[i] = v;
}

__global__ void k_pad(const float* __restrict__ src, unsigned short* __restrict__ dst,
                      int R, int SC, int DC)
{
  int i = blockIdx.x*blockDim.x + threadIdx.x;
  if (i >= R * DC) return;
  int r = i / DC, c = i - r * DC;
  dst[i] = (c < SC) ? f2b(src[r*SC + c]) : (unsigned short)0;
}

__global__ void k_padb(const float* __restrict__ src, float* __restrict__ dst,
                       int R, int SC, int DC)
{
  int i = blockIdx.x*blockDim.x + threadIdx.x;
  if (i >= R * DC) return;
  int r = i / DC, c = i - r * DC;
  dst[i] = (c < SC) ? src[r*SC + c] : 0.f;
}

__global__ void k_h0(const int* __restrict__ x, const unsigned short* __restrict__ x1p,
                     const unsigned short* __restrict__ x2p, unsigned short* __restrict__ h, int N)
{
  const int w = threadIdx.x >> 6, lane = threadIdx.x & 63;
  const int n = blockIdx.x * 4 + w;
  if (n >= N || lane >= 40) return;
  const int c0 = lane * 8;
  const int a = x[2*n], b = x[2*n + 1];
  s16x8 va = *(const s16x8*)&x1p[(size_t)a*EMBP + c0];
  s16x8 vb = *(const s16x8*)&x2p[(size_t)b*EMBP + c0];
  s16x8 o;
#pragma unroll
  for (int j = 0; j < 8; j++)
    o[j] = (short)f2b(b2f((unsigned short)va[j]) + b2f((unsigned short)vb[j]));
  *(s16x8*)&h[(size_t)n*EMBP + c0] = o;
}

// ---------------- aggregation: one wave per node ----------------
// aggr[n] = sum_{incoming e} h[src(e)] + sum_t cnt_t*t1[t] + sum_d cnt_d*t2[d]
// rows [N, Mp) get zeros (pad for GEMM1 staging).
__global__ __launch_bounds__(256) void k_aggr(
    const unsigned short* __restrict__ h,
    const int* __restrict__ rowptr,
    const unsigned int* __restrict__ entries,
    const unsigned short* __restrict__ t1,   // [6][EMBP]
    const unsigned short* __restrict__ t2,   // [3][EMBP]
    unsigned short* __restrict__ aggr, int N, int Mp)
{
  const int w = threadIdx.x >> 6, lane = threadIdx.x & 63;
  const int n = blockIdx.x * 4 + w;
  if (n >= Mp || lane >= 40) return;
  const int c0 = lane * 8;
  float s[8] = {0.f,0.f,0.f,0.f,0.f,0.f,0.f,0.f};
  if (n < N) {
    const int beg = rowptr[n], end = rowptr[n+1];
    int c6[6] = {0,0,0,0,0,0};
    int c3[3] = {0,0,0};
    int e = beg;
    // 4-way unrolled: 4 independent gather loads in flight
    for (; e + 4 <= end; e += 4) {
      const unsigned p0 = entries[e],   p1 = entries[e+1];
      const unsigned p2 = entries[e+2], p3 = entries[e+3];
      s16x8 v0 = *(const s16x8*)&h[(size_t)(p0 & 0xFFFFF)*EMBP + c0];
      s16x8 v1 = *(const s16x8*)&h[(size_t)(p1 & 0xFFFFF)*EMBP + c0];
      s16x8 v2 = *(const s16x8*)&h[(size_t)(p2 & 0xFFFFF)*EMBP + c0];
      s16x8 v3 = *(const s16x8*)&h[(size_t)(p3 & 0xFFFFF)*EMBP + c0];
      const int b0 = (p0 >> 20) & 7, b1_ = (p1 >> 20) & 7, b2_ = (p2 >> 20) & 7, b3 = (p3 >> 20) & 7;
      const int d0 = (p0 >> 24) & 3, d1 = (p1 >> 24) & 3, d2 = (p2 >> 24) & 3, d3 = (p3 >> 24) & 3;
#pragma unroll
      for (int t = 0; t < 6; t++) c6[t] += (b0==t) + (b1_==t) + (b2_==t) + (b3==t);
#pragma unroll
      for (int t = 0; t < 3; t++) c3[t] += (d0==t) + (d1==t) + (d2==t) + (d3==t);
#pragma unroll
      for (int j = 0; j < 8; j++)
        s[j] += b2f((unsigned short)v0[j]) + b2f((unsigned short)v1[j])
              + b2f((unsigned short)v2[j]) + b2f((unsigned short)v3[j]);
    }
    for (; e < end; ++e) {
      const unsigned p = entries[e];
      s16x8 hv = *(const s16x8*)&h[(size_t)(p & 0xFFFFF)*EMBP + c0];
      const int bt = (p >> 20) & 7, bd = (p >> 24) & 3;
#pragma unroll
      for (int t = 0; t < 6; t++) c6[t] += (bt == t);
#pragma unroll
      for (int t = 0; t < 3; t++) c3[t] += (bd == t);
#pragma unroll
      for (int j = 0; j < 8; j++) s[j] += b2f((unsigned short)hv[j]);
    }
#pragma unroll
    for (int t = 0; t < 6; t++) if (c6[t]) {
      s16x8 tv = *(const s16x8*)&t1[t*EMBP + c0];
      const float f = (float)c6[t];
#pragma unroll
      for (int j = 0; j < 8; j++) s[j] += f * b2f((unsigned short)tv[j]);
    }
#pragma unroll
    for (int t = 0; t < 3; t++) if (c3[t]) {
      s16x8 tv = *(const s16x8*)&t2[t*EMBP + c0];
      const float f = (float)c3[t];
#pragma unroll
      for (int j = 0; j < 8; j++) s[j] += f * b2f((unsigned short)tv[j]);
    }
  }
  s16x8 o;
#pragma unroll
  for (int j = 0; j < 8; j++) o[j] = (short)f2b(s[j]);
  *(s16x8*)&aggr[(size_t)n*EMBP + c0] = o;
}

// ---------------- GEMM: C[128x128 tiles] = A[MxKP] * Bt[NtxKP]^T + bias ----
// m97-style: 4 waves 2x2, 4x4 frags/wave, BK=32, gload_lds16, seg-XOR swizzle.
// FIRST: C = bf16 relu, stride HIDP, local rows. else: C = f32 d_out, masked.
template<int KP, bool FIRST>
__global__ __launch_bounds__(256) void k_gemm(
    const unsigned short* __restrict__ A,
    const unsigned short* __restrict__ Bt,
    const float* __restrict__ bias,
    void* __restrict__ Cv,
    int nBase, int N)
{
  __shared__ __align__(16) unsigned short As[128*32];
  __shared__ __align__(16) unsigned short Bs[128*32];
  const int tid = threadIdx.x;
  const int w = tid >> 6, lane = tid & 63;
  const int wr = w >> 1, wc = w & 1;
  const int m0 = blockIdx.x * 128;
  const int n0 = blockIdx.y * 128;

  // staging: 2 x 16B per thread per tile; seg' = seg ^ (row&3) (bank-spread,
  // rule #21: pre-swizzled GLOBAL source + linear LDS dest + swizzled read)
  const int L0 = tid, L1 = tid + 256;
  const int r0 = L0 >> 2, s0 = ((L0 & 3) ^ (r0 & 3)) * 8;
  const int r1 = L1 >> 2, s1 = ((L1 & 3) ^ (r1 & 3)) * 8;
  const unsigned short* Ag0 = A  + (size_t)(m0 + r0)*KP + s0;
  const unsigned short* Ag1 = A  + (size_t)(m0 + r1)*KP + s1;
  const unsigned short* Bg0 = Bt + (size_t)(n0 + r0)*KP + s0;
  const unsigned short* Bg1 = Bt + (size_t)(n0 + r1)*KP + s1;

  f32x4 acc[4][4];
#pragma unroll
  for (int i = 0; i < 4; i++)
#pragma unroll
    for (int j = 0; j < 4; j++)
      acc[i][j] = (f32x4){0.f, 0.f, 0.f, 0.f};

  const int cl = lane & 15;
  const int sw = ((lane >> 4) ^ (lane & 3)) * 8;   // swizzled read offset

  for (int k0 = 0; k0 < KP; k0 += 32) {
    gload16(Ag0 + k0, &As[L0*8]);
    gload16(Ag1 + k0, &As[L1*8]);
    gload16(Bg0 + k0, &Bs[L0*8]);
    gload16(Bg1 + k0, &Bs[L1*8]);
    __syncthreads();
    bfrag af[4], bf[4];
#pragma unroll
    for (int mf = 0; mf < 4; mf++)
      af[mf] = *(const bfrag*)&As[(wr*64 + mf*16 + cl)*32 + sw];
#pragma unroll
    for (int nf = 0; nf < 4; nf++)
      bf[nf] = *(const bfrag*)&Bs[(wc*64 + nf*16 + cl)*32 + sw];
#pragma unroll
    for (int mf = 0; mf < 4; mf++)
#pragma unroll
      for (int nf = 0; nf < 4; nf++)
        acc[mf][nf] = __builtin_amdgcn_mfma_f32_16x16x32_bf16(af[mf], bf[nf], acc[mf][nf], 0, 0, 0);
    __syncthreads();
  }

  const int rg = lane >> 4;
#pragma unroll
  for (int mf = 0; mf < 4; mf++) {
#pragma unroll
    for (int nf = 0; nf < 4; nf++) {
      const int col  = n0 + wc*64 + nf*16 + cl;
      const int row0 = m0 + wr*64 + mf*16 + rg*4;
      f32x4 v = acc[mf][nf];
      if (FIRST) {
        const float bv = bias[col];
#pragma unroll
        for (int r = 0; r < 4; r++)
          ((unsigned short*)Cv)[(size_t)(row0 + r)*HIDP + col] = f2b(fmaxf(v[r] + bv, 0.f));
      } else {
        if (col < EMB) {
          const float bv = bias[col];
#pragma unroll
          for (int r = 0; r < 4; r++) {
            const int grow = nBase + row0 + r;
            if (grow < N)
              ((float*)Cv)[(size_t)grow*EMB + col] = v[r] + bv;
          }
        }
      }
    }
  }
}

// ---------------- BatchNorm (deterministic, f32 activations) ----------------

__global__ void k_bnstat(const float* __restrict__ out, float* __restrict__ part, int N)
{
  const int c = threadIdx.x;   // 0..319
  float s = 0.f, s2 = 0.f;
  if (c < EMB) {
    for (int r = blockIdx.x; r < N; r += gridDim.x) {
      float v = out[(size_t)r*EMB + c];
      s += v; s2 += v*v;
    }
  }
  part[blockIdx.x*(2*EMBP) + c]        = s;
  part[blockIdx.x*(2*EMBP) + EMBP + c] = s2;
}

__global__ void k_bnfin(const float* __restrict__ part,
                        const float* __restrict__ gamma,
                        const float* __restrict__ beta,
                        float* __restrict__ scl, float* __restrict__ sft, int N, int NB)
{
  const int c = threadIdx.x;
  if (c >= EMBP) return;
  float s = 0.f, s2 = 0.f;
  for (int b = 0; b < NB; b++) {
    s  += part[b*(2*EMBP) + c];
    s2 += part[b*(2*EMBP) + EMBP + c];
  }
  if (c < EMB) {
    float mean = s / (float)N;
    float var  = fmaxf(s2 / (float)N - mean*mean, 0.f);
    float sc = gamma[c] * rsqrtf(var + BNEPS);
    scl[c] = sc;
    sft[c] = beta[c] - mean*sc;
  } else { scl[c] = 0.f; sft[c] = 0.f; }
}

template<bool LAST>
__global__ void k_bnapply(const float* __restrict__ outv,
                          const float* __restrict__ scl, const float* __restrict__ sft,
                          unsigned short* __restrict__ hdst, float* __restrict__ odst, int N)
{
  int i = blockIdx.x*blockDim.x + threadIdx.x;
  if (i >= N * (EMBP/4)) return;
  const int n = i / (EMBP/4);
  const int c = (i - n*(EMBP/4)) * 4;
  if (LAST) {
    if (c >= EMB) return;
    f32x4 v = *(const f32x4*)&outv[(size_t)n*EMB + c];
    f32x4 o;
#pragma unroll
    for (int j = 0; j < 4; j++) o[j] = v[j]*scl[c+j] + sft[c+j];
    *(f32x4*)&odst[(size_t)n*EMB + c] = o;
  } else {
    u16x4 o;
    if (c < EMB) {
      f32x4 v = *(const f32x4*)&outv[(size_t)n*EMB + c];
#pragma unroll
      for (int j = 0; j < 4; j++) o[j] = f2b(fmaxf(v[j]*scl[c+j] + sft[c+j], 0.f));
    } else {
#pragma unroll
      for (int j = 0; j < 4; j++) o[j] = 0;
    }
    *(u16x4*)&hdst[(size_t)n*EMBP + c] = o;
  }
}

// ---------------- host ----------------

extern "C" void kernel_launch(void* const* d_in, const int* in_sizes, int n_in,
                              void* d_out, int out_size, void* d_ws, size_t ws_size,
                              hipStream_t stream)
{
  (void)n_in;
  const int* x  = (const int*)d_in[0];
  const int* ei = (const int*)d_in[1];
  const int* ea = (const int*)d_in[2];
  const float* xe1 = (const float*)d_in[3];
  const float* xe2 = (const float*)d_in[4];
  const float* ee1 = (const float*)d_in[5];
  const float* ee2 = (const float*)d_in[6];
  const float* W1  = (const float*)d_in[7];
  const float* b1  = (const float*)d_in[8];
  const float* W2  = (const float*)d_in[9];
  const float* b2  = (const float*)d_in[10];
  const float* gam = (const float*)d_in[11];
  const float* bet = (const float*)d_in[12];

  const int N  = in_sizes[0] / 2;
  const int E  = in_sizes[1] / 2;
  const int EN = E + N;
  const int Mp = ((N + 127) / 128) * 128;
  const int R1 = in_sizes[3] / EMB;

  float* dout = (float*)d_out;
  k_canary<<<1024, 256, 0, stream>>>(dout, out_size);

  char* ws = (char*)d_ws;
  size_t off = 0;
  auto alloc = [&](size_t bytes){ size_t o = off; off = (off + bytes + 255) & ~(size_t)255; return o; };

  unsigned short* h      = (unsigned short*)(ws + alloc((size_t)N*EMBP*2));
  unsigned short* aggr   = (unsigned short*)(ws + alloc((size_t)Mp*EMBP*2));
  unsigned int*  entries = (unsigned int*)(ws + alloc((size_t)EN*4));
  int* rowptr            = (int*)(ws + alloc((size_t)(N+1)*4));
  int* cursor            = (int*)(ws + alloc((size_t)N*4));
  int* deg               = (int*)(ws + alloc((size_t)N*4));
  unsigned short* W1T    = (unsigned short*)(ws + alloc((size_t)NLAYER*HIDP*EMBP*2));
  unsigned short* W2T    = (unsigned short*)(ws + alloc((size_t)NLAYER*EMBP2*HIDP*2));
  unsigned short* x1p    = (unsigned short*)(ws + alloc((size_t)R1*EMBP*2));
  unsigned short* x2p    = (unsigned short*)(ws + alloc((size_t)3*EMBP*2));
  unsigned short* e1p    = (unsigned short*)(ws + alloc((size_t)NLAYER*6*EMBP*2));
  unsigned short* e2p    = (unsigned short*)(ws + alloc((size_t)NLAYER*3*EMBP*2));
  float* b1p             = (float*)(ws + alloc((size_t)NLAYER*HIDP*4));
  float* b2p             = (float*)(ws + alloc((size_t)NLAYER*EMBP*4));
  float* part            = (float*)(ws + alloc((size_t)256*2*EMBP*4));
  float* scl             = (float*)(ws + alloc((size_t)EMBP*4));
  float* sft             = (float*)(ws + alloc((size_t)EMBP*4));

  // adaptive hid chunk (multiple of 128 rows)
  if (off >= ws_size) return;
  size_t avail = ws_size - off;
  size_t maxrows = avail / ((size_t)HIDP*2);
  if (maxrows < 128) return;
  int CH = (maxrows >= (size_t)Mp) ? Mp : (int)(maxrows & ~(size_t)127);
  unsigned short* hidc = (unsigned short*)(ws + off);

  // CSR build
  k_zero<<<(N+255)/256, 256, 0, stream>>>((unsigned int*)deg, N);
  k_hist<<<(EN+255)/256, 256, 0, stream>>>(ei, E, N, deg);
  k_scan<<<1, 1024, 0, stream>>>(deg, rowptr, cursor, N);
  k_fill<<<(EN+255)/256, 256, 0, stream>>>(ei, ea, E, N, cursor, entries);

  // weight/table prep
  {
    int tot1 = NLAYER*HIDP*EMBP;
    k_prep_w<<<(tot1+255)/256, 256, 0, stream>>>(W1, W1T, EMB, HID, EMBP, HIDP);
    int tot2 = NLAYER*EMBP2*HIDP;
    k_prep_w<<<(tot2+255)/256, 256, 0, stream>>>(W2, W2T, HID, EMB, HIDP, EMBP2);
  }
  k_pad <<<((R1*EMBP)+255)/256, 256, 0, stream>>>(xe1, x1p, R1, EMB, EMBP);
  k_pad <<<((3*EMBP)+255)/256, 256, 0, stream>>>(xe2, x2p, 3, EMB, EMBP);
  k_pad <<<((NLAYER*6*EMBP)+255)/256, 256, 0, stream>>>(ee1, e1p, NLAYER*6, EMB, EMBP);
  k_pad <<<((NLAYER*3*EMBP)+255)/256, 256, 0, stream>>>(ee2, e2p, NLAYER*3, EMB, EMBP);
  k_padb<<<((NLAYER*HIDP)+255)/256, 256, 0, stream>>>(b1, b1p, NLAYER, HID, HIDP);
  k_padb<<<((NLAYER*EMBP)+255)/256, 256, 0, stream>>>(b2, b2p, NLAYER, EMB, EMBP);

  k_h0<<<(N+3)/4, 256, 0, stream>>>(x, x1p, x2p, h, N);

  for (int l = 0; l < NLAYER; ++l) {
    k_aggr<<<Mp/4, 256, 0, stream>>>(h, rowptr, entries,
                                     e1p + (size_t)l*6*EMBP, e2p + (size_t)l*3*EMBP,
                                     aggr, N, Mp);
    for (int base = 0; base < Mp; base += CH) {
      const int rows = (Mp - base < CH) ? (Mp - base) : CH;
      dim3 g1(rows/128, HIDP/128);
      k_gemm<EMBP, true><<<g1, 256, 0, stream>>>(
          aggr + (size_t)base*EMBP, W1T + (size_t)l*HIDP*EMBP,
          b1p + (size_t)l*HIDP, hidc, 0, N);
      dim3 g2(rows/128, EMBP2/128);
      k_gemm<HIDP, false><<<g2, 256, 0, stream>>>(
          hidc, W2T + (size_t)l*EMBP2*HIDP,
          b2p + (size_t)l*EMBP, dout, base, N);
    }
    k_bnstat<<<256, EMBP, 0, stream>>>(dout, part, N);
    k_bnfin<<<1, EMBP, 0, stream>>>(part, gam + (size_t)l*EMB, bet + (size_t)l*EMB, scl, sft, N, 256);
    int tot = N * (EMBP/4);
    if (l < NLAYER - 1)
      k_bnapply<false><<<(tot+255)/256, 256, 0, stream>>>(dout, scl, sft, h, nullptr, N);
    else
      k_bnapply<true><<<(tot+255)/256, 256, 0, stream>>>(dout, scl, sft, nullptr, dout, N);
  }
}